// Round 9
// baseline (176.811 us; speedup 1.0000x reference)
//
#include <hip/hip_runtime.h>

// Causal attention fwd, B=2 H=16 S=2048 DK=DV=64, fp32 in/out.
// R9: 1-wave blocks (64 thr), wave owns 64 q (2 subtiles sharing K/V A-frag
// reads -> LDS traffic halved per work). Superstep = 32 kv, dbuf 2x8KB LDS
// (10 blocks/CU), zero barriers, counted vmcnt(8) keeps prefetch in flight
// across compute (T4). Prep writes per-(bh,32kv-tile) 8KB pre-swizzled f16
// images {K 4KB, V^T 4KB}; attn stages via global_load_lds (no staging VGPRs).

#define S_LEN   2048
#define D_DIM   64
#define BH_N    32
#define NEG_BIG (-3.0e38f)
#define CSCALE  0.18033688011112042f   // log2(e)/sqrt(64)

typedef float     f32x16 __attribute__((ext_vector_type(16)));
typedef _Float16  f16x8  __attribute__((ext_vector_type(8)));
typedef __fp16    fp16x2 __attribute__((ext_vector_type(2)));
typedef unsigned int   u32;
typedef unsigned short u16;

__device__ __forceinline__ u32 pkrtz2(float a, float b) {
  union { fp16x2 h; u32 u; } U;
  U.h = __builtin_amdgcn_cvt_pkrtz(a, b);
  return U.u;
}

__device__ __forceinline__ void plswap(u32& a, u32& b) {
  auto r = __builtin_amdgcn_permlane32_swap((int)a, (int)b, false, false);
  a = (u32)r[0]; b = (u32)r[1];
}

__device__ __forceinline__ f32x16 mfma16(f16x8 a, f16x8 b, f32x16 c) {
  return __builtin_amdgcn_mfma_f32_32x32x16_f16(a, b, c, 0, 0, 0);
}

__device__ __forceinline__ void gload_lds16(const void* g, void* l) {
  __builtin_amdgcn_global_load_lds(
      (const __attribute__((address_space(1))) u32*)g,
      (__attribute__((address_space(3))) u32*)l, 16, 0, 0);
}

// K image: 32 kv x 64 d f16 in 4KB. 16 rows of 256B = kv pair (2R,2R+1).
// ci = (dchunk*2 + (kv&1)) ^ ((R&7)<<1); uniform ci coverage -> conflict-free.
__device__ __forceinline__ f16x8 fragK(const u16* base, int kv, int dchunk) {
  const u32 R  = (u32)kv >> 1;
  const u32 ci = ((u32)dchunk * 2 + ((u32)kv & 1)) ^ ((R & 7) << 1);
  return *(const f16x8*)((const char*)base + R * 256 + ci * 16);
}
// V^T image: 64 dv x 32 kv f16 in 4KB. 32 rows of 128B = dv pair (2D,2D+1).
// ci = (kvchunk*2 + (dv&1)) ^ (D&7).
__device__ __forceinline__ f16x8 fragV(const u16* base, int dv, int kvchunk) {
  const u32 D  = (u32)dv >> 1;
  const u32 ci = ((u32)kvchunk * 2 + ((u32)dv & 1)) ^ (D & 7);
  return *(const f16x8*)((const char*)base + D * 128 + ci * 16);
}

// ---- prep: per (bh, 32-kv tile) 8KB image: [0,4K) K, [4K,8K) V^T ----
__global__ __launch_bounds__(256) void prep_kernel(const float* __restrict__ K,
                                                   const float* __restrict__ V,
                                                   u16* __restrict__ img) {
  __shared__ __align__(16) float vbuf[128 * 64];   // 32KB, chunk-swizzled
  const int bid  = blockIdx.x;         // 512 = 32 bh * 16
  const int bh   = bid & 31;
  const int sidx = bid >> 5;
  const int kb   = sidx * 128;
  const int t    = threadIdx.x;
  const int kvS  = t & 127;
  const int dh   = t >> 7;             // which 32-d half

  { // K -> K image (cvt f32->f16, pre-swizzled positions)
    const float* kg = K + ((size_t)bh * S_LEN + kb + kvS) * D_DIM + dh * 32;
    float fv[32];
    #pragma unroll
    for (int i = 0; i < 8; ++i) {
      float4 a = *(const float4*)(kg + 4 * i);
      fv[4 * i + 0] = a.x; fv[4 * i + 1] = a.y;
      fv[4 * i + 2] = a.z; fv[4 * i + 3] = a.w;
    }
    const int tile_g = bh * 64 + sidx * 4 + (kvS >> 5);
    char* ibK = (char*)img + (size_t)tile_g * 8192;
    const u32 R = ((u32)kvS & 31) >> 1, par = (u32)kvS & 1;
    #pragma unroll
    for (int c = 0; c < 4; ++c) {
      uint4 d = make_uint4(pkrtz2(fv[8*c+0], fv[8*c+1]), pkrtz2(fv[8*c+2], fv[8*c+3]),
                           pkrtz2(fv[8*c+4], fv[8*c+5]), pkrtz2(fv[8*c+6], fv[8*c+7]));
      const u32 dchunk = (u32)dh * 4 + c;
      const u32 ci = (dchunk * 2 + par) ^ ((R & 7) << 1);
      *(uint4*)(ibK + R * 256 + ci * 16) = d;
    }
  }
  { // V -> LDS f32 (chunk-swizzled for conflict-free column reads)
    const float* vg = V + ((size_t)bh * S_LEN + kb + kvS) * D_DIM + dh * 32;
    #pragma unroll
    for (int i = 0; i < 8; ++i) {
      float4 a = *(const float4*)(vg + 4 * i);
      const u32 c4 = (u32)dh * 8 + i;
      *(float4*)((char*)vbuf + kvS * 256 + ((c4 ^ ((u32)kvS & 15)) * 16)) = a;
    }
  }
  __syncthreads();
  { // LDS -> V^T images (transpose + cvt)
    const int dv = t & 63, kq = t >> 6;
    u32 wv[16];
    #pragma unroll
    for (int j = 0; j < 16; ++j) {
      const int k0 = kq * 32 + 2 * j, k1 = k0 + 1;
      float f0 = *(const float*)((char*)vbuf + k0 * 256 +
                  ((((u32)dv >> 2) ^ ((u32)k0 & 15)) * 16) + (dv & 3) * 4);
      float f1 = *(const float*)((char*)vbuf + k1 * 256 +
                  ((((u32)dv >> 2) ^ ((u32)k1 & 15)) * 16) + (dv & 3) * 4);
      wv[j] = pkrtz2(f0, f1);
    }
    const int tile_g = bh * 64 + sidx * 4 + kq;
    char* ibV = (char*)img + (size_t)tile_g * 8192 + 4096;
    const u32 D = (u32)dv >> 1, vpar = (u32)dv & 1;
    #pragma unroll
    for (int x = 0; x < 4; ++x) {
      const u32 ci = ((u32)x * 2 + vpar) ^ (D & 7);
      *(uint4*)(ibV + D * 128 + ci * 16) =
          make_uint4(wv[4*x+0], wv[4*x+1], wv[4*x+2], wv[4*x+3]);
    }
  }
}

// softmax over one 32-kv tile's scores for one q-subtile; packs P into pf[8]
__device__ __forceinline__ void softmax_pack(f32x16 sc, bool diag, int lo31, int hi,
                                             float& m_run, float& r_sum,
                                             f32x16& oA, f32x16& oB, u32 pf[8]) {
  if (diag) {
    #pragma unroll
    for (int i = 0; i < 16; ++i) {
      const int kvloc = (i & 3) + 8 * (i >> 2) + 4 * hi;
      if (kvloc > lo31) sc[i] = NEG_BIG;
    }
  }
  float t8[8];
  #pragma unroll
  for (int i = 0; i < 8; ++i) t8[i] = fmaxf(sc[i], sc[i + 8]);
  float t4a = fmaxf(t8[0], t8[4]), t4b = fmaxf(t8[1], t8[5]);
  float t4c = fmaxf(t8[2], t8[6]), t4d = fmaxf(t8[3], t8[7]);
  float mt = fmaxf(fmaxf(t4a, t4b), fmaxf(t4c, t4d));
  mt = fmaxf(mt, __shfl_xor(mt, 32, 64));
  if (!__all(mt <= m_run + 8.0f)) {            // defer-max (T13)
    const float mn = fmaxf(m_run, mt);
    const float rs = __builtin_amdgcn_exp2f(m_run - mn);
    m_run = mn;
    r_sum *= rs;
    #pragma unroll
    for (int i = 0; i < 16; ++i) { oA[i] *= rs; oB[i] *= rs; }
  }
  float psum = 0.0f;
  #pragma unroll
  for (int j = 0; j < 8; ++j) {
    float pa = __builtin_amdgcn_exp2f(sc[2 * j]     - m_run);
    float pb = __builtin_amdgcn_exp2f(sc[2 * j + 1] - m_run);
    psum += pa + pb;
    pf[j] = pkrtz2(pa, pb);
  }
  psum += __shfl_xor(psum, 32, 64);
  r_sum += psum;
  plswap(pf[0], pf[2]); plswap(pf[1], pf[3]);   // C/D -> B-frag layout (T12)
  plswap(pf[4], pf[6]); plswap(pf[5], pf[7]);
}

// ---------------- main flash attention: 1 wave per block ----------------
__global__ __launch_bounds__(64, 2) void attn_kernel(const float* __restrict__ Q,
                                                     const u16* __restrict__ img,
                                                     float* __restrict__ Out) {
  __shared__ __align__(16) u16 BUF[2][4096];   // 2 x 8KB double buffer

  const int bid = blockIdx.x;          // 1024 = 32 bh * 32 qt
  const int bh  = bid & 31;
  const int qt  = 31 - (bid >> 5);     // biggest causal jobs first
  const int l   = threadIdx.x;         // 0..63
  const int lo31 = l & 31;
  const int hi  = l >> 5;
  const int qb0 = qt * 64;             // qs0 rows [qb0,qb0+32), qs1 +32
  const int qb1 = qb0 + 32;

  // Q frags per q-subtile (f16, scale folded): col=q=lane&31, k=d=kk*16+hi*8+j
  f16x8 qf0[4], qf1[4];
  {
    const float* qp0 = Q + ((size_t)bh * S_LEN + qb0 + lo31) * D_DIM;
    const float* qp1 = qp0 + 32 * D_DIM;
    #pragma unroll
    for (int kk = 0; kk < 4; ++kk) {
      const int dd = kk * 16 + hi * 8;
      float4 a0 = *(const float4*)(qp0 + dd);
      float4 b0 = *(const float4*)(qp0 + dd + 4);
      float4 a1 = *(const float4*)(qp1 + dd);
      float4 b1 = *(const float4*)(qp1 + dd + 4);
      union { u32 u[4]; f16x8 v; } U0, U1;
      U0.u[0] = pkrtz2(a0.x * CSCALE, a0.y * CSCALE);
      U0.u[1] = pkrtz2(a0.z * CSCALE, a0.w * CSCALE);
      U0.u[2] = pkrtz2(b0.x * CSCALE, b0.y * CSCALE);
      U0.u[3] = pkrtz2(b0.z * CSCALE, b0.w * CSCALE);
      U1.u[0] = pkrtz2(a1.x * CSCALE, a1.y * CSCALE);
      U1.u[1] = pkrtz2(a1.z * CSCALE, a1.w * CSCALE);
      U1.u[2] = pkrtz2(b1.x * CSCALE, b1.y * CSCALE);
      U1.u[3] = pkrtz2(b1.z * CSCALE, b1.w * CSCALE);
      qf0[kk] = U0.v; qf1[kk] = U1.v;
    }
  }

  f32x16 o00 = {}, o01 = {};   // qs0: dv 0..31 / 32..63 (col=q, row per C/D map)
  f32x16 o10 = {}, o11 = {};   // qs1
  float m0 = NEG_BIG, m1 = NEG_BIG, r0 = 0.0f, r1 = 0.0f;

  const char* gimg = (const char*)img + (size_t)bh * (64 * 8192);
  auto issue = [&](int s, int b) {     // stage 8KB tile: 8 x gload_lds16
    const char* g = gimg + (size_t)s * 8192 + (u32)(l * 16);
    char* lp = (char*)&BUF[b][0];
    #pragma unroll
    for (int j = 0; j < 8; ++j)
      gload_lds16(g + j * 1024, lp + j * 1024);
  };

  const int NS = 2 * qt + 2;           // 32-kv tiles covering kv <= qb1+31

  issue(0, 0);
  for (int s = 0; s < NS; ++s) {
    if (s + 1 < NS) {
      issue(s + 1, (s + 1) & 1);       // prefetch stays in flight (T4)
      asm volatile("s_waitcnt vmcnt(8)" ::: "memory");   // only L_s drained
    } else {
      asm volatile("s_waitcnt vmcnt(0)" ::: "memory");
    }
    __builtin_amdgcn_sched_barrier(0);

    const u16* Kb = &BUF[s & 1][0];
    const u16* Vb = &BUF[s & 1][2048];
    const int kb = 32 * s;
    const bool a0 = (kb <= qb0);

    // K frags shared across both q-subtiles
    f16x8 kf0 = fragK(Kb, lo31, 0 + hi);
    f16x8 kf1 = fragK(Kb, lo31, 2 + hi);
    f16x8 kf2 = fragK(Kb, lo31, 4 + hi);
    f16x8 kf3 = fragK(Kb, lo31, 6 + hi);

    u32 p0[8], p1[8];
    if (a0) {
      f32x16 sc = {};
      __builtin_amdgcn_s_setprio(1);
      sc = mfma16(kf0, qf0[0], sc);
      sc = mfma16(kf1, qf0[1], sc);
      sc = mfma16(kf2, qf0[2], sc);
      sc = mfma16(kf3, qf0[3], sc);
      __builtin_amdgcn_s_setprio(0);
      softmax_pack(sc, kb == qb0, lo31, hi, m0, r0, o00, o01, p0);
    }
    {
      f32x16 sc = {};
      __builtin_amdgcn_s_setprio(1);
      sc = mfma16(kf0, qf1[0], sc);
      sc = mfma16(kf1, qf1[1], sc);
      sc = mfma16(kf2, qf1[2], sc);
      sc = mfma16(kf3, qf1[3], sc);
      __builtin_amdgcn_s_setprio(0);
      softmax_pack(sc, kb == qb1, lo31, hi, m1, r1, o10, o11, p1);
    }

    // PV: V frags shared across both q-subtiles
    __builtin_amdgcn_s_setprio(1);
    #pragma unroll
    for (int ks = 0; ks < 2; ++ks) {
      f16x8 vfA = fragV(Vb, lo31,      ks * 2 + hi);
      f16x8 vfB = fragV(Vb, 32 + lo31, ks * 2 + hi);
      union { u32 u[4]; f16x8 v; } P1;
      P1.u[0] = p1[4*ks+0]; P1.u[1] = p1[4*ks+1];
      P1.u[2] = p1[4*ks+2]; P1.u[3] = p1[4*ks+3];
      o10 = mfma16(vfA, P1.v, o10);
      o11 = mfma16(vfB, P1.v, o11);
      if (a0) {
        union { u32 u[4]; f16x8 v; } P0;
        P0.u[0] = p0[4*ks+0]; P0.u[1] = p0[4*ks+1];
        P0.u[2] = p0[4*ks+2]; P0.u[3] = p0[4*ks+3];
        o00 = mfma16(vfA, P0.v, o00);
        o01 = mfma16(vfB, P0.v, o01);
      }
    }
    __builtin_amdgcn_s_setprio(0);
  }

  // ---- epilogue: normalize + store (no merge needed) ----
  {
    const float inv = 1.0f / r0;
    float* op = Out + ((size_t)bh * S_LEN + qb0 + lo31) * D_DIM;
    #pragma unroll
    for (int g = 0; g < 4; ++g) {
      float4 sA = make_float4(o00[4*g+0]*inv, o00[4*g+1]*inv, o00[4*g+2]*inv, o00[4*g+3]*inv);
      float4 sB = make_float4(o01[4*g+0]*inv, o01[4*g+1]*inv, o01[4*g+2]*inv, o01[4*g+3]*inv);
      *(float4*)(op + g * 8 + hi * 4)      = sA;   // dv = 8g + 4*hi + 0..3
      *(float4*)(op + 32 + g * 8 + hi * 4) = sB;   // dv + 32
    }
  }
  {
    const float inv = 1.0f / r1;
    float* op = Out + ((size_t)bh * S_LEN + qb1 + lo31) * D_DIM;
    #pragma unroll
    for (int g = 0; g < 4; ++g) {
      float4 sA = make_float4(o10[4*g+0]*inv, o10[4*g+1]*inv, o10[4*g+2]*inv, o10[4*g+3]*inv);
      float4 sB = make_float4(o11[4*g+0]*inv, o11[4*g+1]*inv, o11[4*g+2]*inv, o11[4*g+3]*inv);
      *(float4*)(op + g * 8 + hi * 4)      = sA;
      *(float4*)(op + 32 + g * 8 + hi * 4) = sB;
    }
  }
}

extern "C" void kernel_launch(void* const* d_in, const int* in_sizes, int n_in,
                              void* d_out, int out_size, void* d_ws, size_t ws_size,
                              hipStream_t stream) {
  const float* Q = (const float*)d_in[0];
  const float* K = (const float*)d_in[1];
  const float* V = (const float*)d_in[2];
  // d_in[3] = tril mask: handled analytically (causal), not read.
  float* Out = (float*)d_out;
  u16* img = (u16*)d_ws;               // 32 bh * 64 tiles * 8KB = 16.8 MB
  prep_kernel<<<dim3(BH_N * 16), dim3(256), 0, stream>>>(K, V, img);
  attn_kernel<<<dim3(BH_N * 32), dim3(64), 0, stream>>>(Q, img, Out);
}